// Round 13
// baseline (42.853 us; speedup 1.0000x reference)
//
#include <hip/hip_runtime.h>
#include <hip/hip_bf16.h>

// KoLeo loss, B=8192, D=256, TOPK=1.
// loss = mean_i( -log( ||x_i - x_{nn(i)}|| + 2*EPS ) ),  x = row-normalize(input)
// nn(i) = argmax_{j!=i} dot(x_i, x_j)  -- selection via INT8 MFMA Gram scan
// (q = round(360*x_hat), i32 dots, packed-index int max); selected distance
// recomputed exactly in fp32. Atomic-free merge via part[32][8192].
//
// r12 lesson: reg diet -> 4 waves/SIMD gained 9us; remaining argmax gap is
// the LDS staging+barrier apparatus itself -- staging data that is fully
// L2-resident (q8 = 2 MB < 4 MB/XCD L2) is pure overhead (guide mistake #7).
// This round: NO LDS, NO barriers. 1-wave blocks; each wave owns 128 cols
// (4 B-sets, 128 regs) and streams its 256-row slice straight from L2 with
// ILP-8 dwordx4 loads; 4 independent MFMA chains; grid (64,32)=2048 waves =
// exactly 2 waves/SIMD device-wide (launch_bounds(64,2) caps regs at 256).

#define NB 8192
#define ND 256
#define QROWB 256         // bytes per row of i8 q
#define EPSF 1e-8f
#define WCOLS 128         // owned cols per wave (4 sets of 32)
#define CSL 256           // streamed rows per slice
#define NSL (NB / CSL)    // 32 slices
#define QSCALE 360.0f

typedef __attribute__((ext_vector_type(4))) int i32x4;
typedef __attribute__((ext_vector_type(16))) int i32x16;
typedef unsigned long long ull;

__device__ __forceinline__ int imax(int a, int b) { return a > b ? a : b; }

// ---------------- Phase A: row L2-normalize -> i8 quant + norms ---------------
__global__ __launch_bounds__(256) void koleo_normalize(const float* __restrict__ s,
                                                       unsigned int* __restrict__ q32,
                                                       float* __restrict__ norms) {
    const int w = threadIdx.x >> 6, lane = threadIdx.x & 63;
    const int row = blockIdx.x * 4 + w;
    const float4 v = *(const float4*)(s + row * ND + lane * 4);
    float ss = v.x * v.x + v.y * v.y + v.z * v.z + v.w * v.w;
    #pragma unroll
    for (int m = 32; m; m >>= 1) ss += __shfl_xor(ss, m);
    const float nrm = sqrtf(ss);
    const float qs = QSCALE / (nrm + EPSF);
    const int a0 = __float2int_rn(fmaxf(-127.f, fminf(127.f, v.x * qs)));
    const int a1 = __float2int_rn(fmaxf(-127.f, fminf(127.f, v.y * qs)));
    const int a2 = __float2int_rn(fmaxf(-127.f, fminf(127.f, v.z * qs)));
    const int a3 = __float2int_rn(fmaxf(-127.f, fminf(127.f, v.w * qs)));
    const unsigned pk = (unsigned)(a0 & 255) | ((unsigned)(a1 & 255) << 8) |
                        ((unsigned)(a2 & 255) << 16) | ((unsigned)(a3 & 255) << 24);
    q32[row * (QROWB / 4) + lane] = pk;
    if (lane == 0) norms[row] = nrm;
}

// ---------------- Phase B: barrier-free L2-direct i8 MFMA argmax --------------
// grid (NB/WCOLS, NSL) = (64, 32) = 2048 one-wave blocks; 2 waves/SIMD.
// D layout (32x32x32): col = lane&31, row = (r&3) + 8*(r>>2) + 4*(lane>>5).
// k-halves: lanes 0-31 accumulate dims 0..127, lanes 32-63 dims 128..255;
// merged with one shfl_xor(32) at the end (disjoint row-partials? no --
// disjoint K-partials of the SAME (row,col) dots; max over rows commutes).
__global__ __launch_bounds__(64, 2) void koleo_argmax(const char* __restrict__ q8,
                                                      ull* __restrict__ part) {
    const int lane = threadIdx.x;
    const int col = lane & 31;
    const int h = lane >> 5;               // k-half selector
    const int hq = h << 2;                 // D-row bit 2 (kept OUT of packed keys)
    const int cb = blockIdx.x;             // 128-col block
    const int sb = blockIdx.y;             // 256-row slice
    const int sbase = sb * CSL;
    const int colbase = cb * WCOLS;
    const bool hasdiag = ((cb >> 1) == (int)sb);
    const int ilocb = ((cb & 1) << 7) + col;   // iloc for set g = ilocb + g*32

    // owned-col B fragments: 4 sets x 8 k-steps x 16 i8 (128 regs)
    i32x4 bfr[4][8];
    #pragma unroll
    for (int g = 0; g < 4; ++g) {
        const char* bp = q8 + (size_t)(colbase + g * 32 + col) * QROWB + h * 16;
        #pragma unroll
        for (int ks = 0; ks < 8; ++ks) bfr[g][ks] = *(const i32x4*)(bp + ks * 32);
    }

    int bd0 = (int)0x80000000, bd1 = (int)0x80000000;
    int bd2 = (int)0x80000000, bd3 = (int)0x80000000;

    // A stream base: row (sbase + sub*32 + col), k-slot (2ks+h)
    const char* arow = q8 + ((size_t)(sbase + col) * QROWB) + h * 16;

    #pragma unroll
    for (int sub = 0; sub < 8; ++sub) {
        // issue all 8 A-loads back-to-back (ILP-8; L2-hit ~200cy hidden by
        // the previous sub's MFMA stream)
        i32x4 av[8];
        const char* ap = arow + (size_t)sub * (32 * QROWB);
        #pragma unroll
        for (int ks = 0; ks < 8; ++ks) av[ks] = *(const i32x4*)(ap + ks * 32);

        i32x16 a0, a1, a2, a3;
        #pragma unroll
        for (int z = 0; z < 16; ++z) { a0[z] = 0; a1[z] = 0; a2[z] = 0; a3[z] = 0; }
        #pragma unroll
        for (int ks = 0; ks < 8; ++ks) {
            a0 = __builtin_amdgcn_mfma_i32_32x32x32_i8(av[ks], bfr[0][ks], a0, 0, 0, 0);
            a1 = __builtin_amdgcn_mfma_i32_32x32x32_i8(av[ks], bfr[1][ks], a1, 0, 0, 0);
            a2 = __builtin_amdgcn_mfma_i32_32x32x32_i8(av[ks], bfr[2][ks], a2, 0, 0, 0);
            a3 = __builtin_amdgcn_mfma_i32_32x32x32_i8(av[ks], bfr[3][ks], a3, 0, 0, 0);
        }
        // packed key = dot*256 + c, c = sub*32 + rofs (uniform; bit 2 = hq slot)
        const int cbse = sub * 32;
        if (hasdiag) {
            #pragma unroll
            for (int r = 0; r < 16; ++r) {
                const int rofs = (r & 3) + 8 * (r >> 2);
                const int c = cbse + rofs;
                const int lrf = c + hq;
                int k0 = a0[r] * 256 + c; if (lrf == ilocb)       k0 = (int)0x80000000;
                int k1 = a1[r] * 256 + c; if (lrf == ilocb + 32)  k1 = (int)0x80000000;
                int k2 = a2[r] * 256 + c; if (lrf == ilocb + 64)  k2 = (int)0x80000000;
                int k3 = a3[r] * 256 + c; if (lrf == ilocb + 96)  k3 = (int)0x80000000;
                bd0 = imax(bd0, k0); bd1 = imax(bd1, k1);
                bd2 = imax(bd2, k2); bd3 = imax(bd3, k3);
            }
        } else {
            #pragma unroll
            for (int r = 0; r < 16; r += 2) {
                const int cA = cbse + ((r & 3) + 8 * (r >> 2));
                const int cB = cbse + (((r + 1) & 3) + 8 * ((r + 1) >> 2));
                bd0 = imax(imax(a0[r] * 256 + cA, a0[r + 1] * 256 + cB), bd0);
                bd1 = imax(imax(a1[r] * 256 + cA, a1[r + 1] * 256 + cB), bd1);
                bd2 = imax(imax(a2[r] * 256 + cA, a2[r + 1] * 256 + cB), bd2);
                bd3 = imax(imax(a3[r] * 256 + cA, a3[r + 1] * 256 + cB), bd3);
            }
        }
    }

    // restore hq bit, merge the two k-halves, plain-store per-slice winners
    ull* prow = part + (size_t)sb * NB;
    int bd[4] = {bd0 | hq, bd1 | hq, bd2 | hq, bd3 | hq};
    #pragma unroll
    for (int g = 0; g < 4; ++g) {
        int b = bd[g];
        const int o = __shfl_xor(b, 32);
        b = imax(b, o);
        if (lane < 32) {
            const unsigned uk = (unsigned)b ^ 0x80000000u;
            const unsigned j = (unsigned)(sbase + (b & 255));
            prow[colbase + g * 32 + col] = ((ull)uk << 32) | j;
        }
    }
}

// ---------------- Phase C: merge slices + exact fp32 distances ----------------
// grid NB/16 = 512 blocks; 4 waves/block; each wave handles 4 rows.
__global__ __launch_bounds__(256) void koleo_dist(const float* __restrict__ s,
                                                  const float* __restrict__ norms,
                                                  const ull* __restrict__ part,
                                                  float* __restrict__ partial) {
    __shared__ float wsums[4];
    const int w = threadIdx.x >> 6, lane = threadIdx.x & 63;
    float acc = 0.f;
    #pragma unroll
    for (int t = 0; t < 4; ++t) {
        const int i = blockIdx.x * 16 + w * 4 + t;
        // merge the 32 per-slice winners for row i (u64 butterfly max)
        ull k = part[(size_t)(lane & 31) * NB + i];
        #pragma unroll
        for (int m = 1; m < 32; m <<= 1) {
            const ull o = __shfl_xor(k, m);
            if (o > k) k = o;
        }
        const int j = (int)(k & 0xFFFFFFFFull);
        const float sci = 1.0f / (norms[i] + EPSF);
        const float scj = 1.0f / (norms[j] + EPSF);
        const float4 vi = *(const float4*)(s + i * ND + lane * 4);
        const float4 vj = *(const float4*)(s + j * ND + lane * 4);
        const float dx = vi.x * sci - vj.x * scj;
        const float dy = vi.y * sci - vj.y * scj;
        const float dz = vi.z * sci - vj.z * scj;
        const float dw = vi.w * sci - vj.w * scj;
        float d2 = dx * dx + dy * dy + dz * dz + dw * dw;
        #pragma unroll
        for (int mask = 32; mask; mask >>= 1) d2 += __shfl_xor(d2, mask);
        acc += -logf(sqrtf(d2) + EPSF + EPSF);
    }
    if (lane == 0) wsums[w] = acc;
    __syncthreads();
    if (threadIdx.x == 0) partial[blockIdx.x] = wsums[0] + wsums[1] + wsums[2] + wsums[3];
}

// ---------------- Phase D: final reduce (512 partials) ------------------------
__global__ __launch_bounds__(512) void koleo_final(const float* __restrict__ partial,
                                                   float* __restrict__ out) {
    __shared__ float w8[8];
    float v = partial[threadIdx.x];
    #pragma unroll
    for (int mask = 32; mask; mask >>= 1) v += __shfl_xor(v, mask);
    if ((threadIdx.x & 63) == 0) w8[threadIdx.x >> 6] = v;
    __syncthreads();
    if (threadIdx.x == 0) {
        float t = 0.f;
        #pragma unroll
        for (int k = 0; k < 8; ++k) t += w8[k];
        out[0] = t / (float)NB;
    }
}

extern "C" void kernel_launch(void* const* d_in, const int* in_sizes, int n_in,
                              void* d_out, int out_size, void* d_ws, size_t ws_size,
                              hipStream_t stream) {
    const float* s = (const float*)d_in[0];
    float* out = (float*)d_out;
    char* ws = (char*)d_ws;

    // ws layout
    char* q8 = ws;                                                          // 2 MiB i8 q
    float* norms = (float*)(ws + 2 * 1024 * 1024);                          // 32 KiB
    ull* part = (ull*)(ws + 2 * 1024 * 1024 + 32 * 1024);                   // 2 MiB (32 x 8192 u64)
    float* partial = (float*)(ws + 4 * 1024 * 1024 + 64 * 1024);            // 2 KiB

    koleo_normalize<<<NB / 4, 256, 0, stream>>>(s, (unsigned int*)q8, norms);
    koleo_argmax<<<dim3(NB / WCOLS, NSL), 64, 0, stream>>>(q8, part);
    koleo_dist<<<NB / 16, 256, 0, stream>>>(s, norms, part, partial);
    koleo_final<<<1, 512, 0, stream>>>(partial, out);
}

// Round 14
// 34.883 us; speedup vs baseline: 1.2285x; 1.2285x over previous
//
#include <hip/hip_runtime.h>
#include <hip/hip_bf16.h>

// KoLeo loss, B=8192, D=256, TOPK=1.
// loss = mean_i( -log( ||x_i - x_{nn(i)}|| + 2*EPS ) ),  x = row-normalize(input)
// nn(i) = argmax_{j!=i} dot(x_i, x_j)  -- selection via INT8 MFMA Gram scan
// (q = round(360*x_hat), i32 dots, packed-index int max); selected distance
// recomputed exactly in fp32. Atomic-free merge via part[32][8192].
//
// r13 lesson: L2-direct with row-major q8 regressed 4x on L2 request
// amplification (16B/lane at 256B stride = 64 lines per instr). This round:
// normalize writes q in MFMA-FRAGMENT-TILED layout qt[a][ks][(h,col)] (16B
// chunks), so every argmax load -- streamed A fragments AND owned-col B
// fragments -- is 64 lanes x 16B = one contiguous 1KB block. No LDS, no
// barriers, no swizzle. Same fragment mapping / masking as r12/r13 (absmax 0).

#define NB 8192
#define ND 256
#define EPSF 1e-8f
#define WCOLS 128         // owned cols per wave (4 sets of 32)
#define CSL 256           // streamed rows per slice
#define NSL (NB / CSL)    // 32 slices
#define QSCALE 360.0f

typedef __attribute__((ext_vector_type(4))) int i32x4;
typedef __attribute__((ext_vector_type(16))) int i32x16;
typedef unsigned long long ull;

__device__ __forceinline__ int imax(int a, int b) { return a > b ? a : b; }

// ---------------- Phase A: row L2-normalize -> fragment-tiled i8 + norms ------
// qt chunk index = (a*8 + ks)*64 + h*32 + col   (16B chunks)
//   a = row>>5, col = row&31, ks = k>>5, h = (k>>4)&1  (k = dim index)
// Thread (row, lane) holds dims k = lane*4..lane*4+3 -> one u32 at
//   u32_idx = ((a*8 + (lane>>3))*64 + ((lane>>2)&1)*32 + col)*4 + (lane&3)
__global__ __launch_bounds__(256) void koleo_normalize(const float* __restrict__ s,
                                                       unsigned int* __restrict__ qt,
                                                       float* __restrict__ norms) {
    const int w = threadIdx.x >> 6, lane = threadIdx.x & 63;
    const int row = blockIdx.x * 4 + w;
    const float4 v = *(const float4*)(s + row * ND + lane * 4);
    float ss = v.x * v.x + v.y * v.y + v.z * v.z + v.w * v.w;
    #pragma unroll
    for (int m = 32; m; m >>= 1) ss += __shfl_xor(ss, m);
    const float nrm = sqrtf(ss);
    const float qs = QSCALE / (nrm + EPSF);
    const int a0 = __float2int_rn(fmaxf(-127.f, fminf(127.f, v.x * qs)));
    const int a1 = __float2int_rn(fmaxf(-127.f, fminf(127.f, v.y * qs)));
    const int a2 = __float2int_rn(fmaxf(-127.f, fminf(127.f, v.z * qs)));
    const int a3 = __float2int_rn(fmaxf(-127.f, fminf(127.f, v.w * qs)));
    const unsigned pk = (unsigned)(a0 & 255) | ((unsigned)(a1 & 255) << 8) |
                        ((unsigned)(a2 & 255) << 16) | ((unsigned)(a3 & 255) << 24);
    const int a = row >> 5, col = row & 31;
    const int ks = lane >> 3, h = (lane >> 2) & 1;
    qt[((a * 8 + ks) * 64 + h * 32 + col) * 4 + (lane & 3)] = pk;
    if (lane == 0) norms[row] = nrm;
}

// ---------------- Phase B: barrier-free L2-direct i8 MFMA argmax --------------
// grid (NB/WCOLS, NSL) = (64, 32) = 2048 one-wave blocks; 2 waves/SIMD.
// All loads are 1KB-contiguous fragments from qt. D layout (32x32x32):
// col = lane&31, row = (r&3) + 8*(r>>2) + 4*(lane>>5).
__global__ __launch_bounds__(64, 2) void koleo_argmax(const i32x4* __restrict__ qt,
                                                      ull* __restrict__ part) {
    const int lane = threadIdx.x;
    const int col = lane & 31;
    const int h = lane >> 5;               // k-half selector
    const int hq = h << 2;                 // D-row bit 2 (kept OUT of packed keys)
    const int cb = blockIdx.x;             // 128-col block
    const int sb = blockIdx.y;             // 256-row slice
    const int sbase = sb * CSL;
    const int colbase = cb * WCOLS;
    const bool hasdiag = ((cb >> 1) == (int)sb);
    const int ilocb = ((cb & 1) << 7) + col;   // iloc for set g = ilocb + g*32

    // owned-col B fragments: qt[(cb*4+g)*8 + ks] + lane  (1KB contiguous each)
    i32x4 bfr[4][8];
    #pragma unroll
    for (int g = 0; g < 4; ++g) {
        const i32x4* bp = qt + (size_t)(cb * 32 + g * 8) * 64 + lane;
        #pragma unroll
        for (int ks = 0; ks < 8; ++ks) bfr[g][ks] = bp[ks * 64];
    }

    int bd0 = (int)0x80000000, bd1 = (int)0x80000000;
    int bd2 = (int)0x80000000, bd3 = (int)0x80000000;

    // A stream: fragment (a = sb*8 + sub, ks) at qt[(a*8+ks)*64 + lane]
    const i32x4* abase = qt + (size_t)(sb * 64) * 64 + lane;

    #pragma unroll
    for (int sub = 0; sub < 8; ++sub) {
        i32x4 av[8];
        const i32x4* ap = abase + (size_t)sub * 8 * 64;
        #pragma unroll
        for (int ks = 0; ks < 8; ++ks) av[ks] = ap[ks * 64];

        i32x16 a0, a1, a2, a3;
        #pragma unroll
        for (int z = 0; z < 16; ++z) { a0[z] = 0; a1[z] = 0; a2[z] = 0; a3[z] = 0; }
        #pragma unroll
        for (int ks = 0; ks < 8; ++ks) {
            a0 = __builtin_amdgcn_mfma_i32_32x32x32_i8(av[ks], bfr[0][ks], a0, 0, 0, 0);
            a1 = __builtin_amdgcn_mfma_i32_32x32x32_i8(av[ks], bfr[1][ks], a1, 0, 0, 0);
            a2 = __builtin_amdgcn_mfma_i32_32x32x32_i8(av[ks], bfr[2][ks], a2, 0, 0, 0);
            a3 = __builtin_amdgcn_mfma_i32_32x32x32_i8(av[ks], bfr[3][ks], a3, 0, 0, 0);
        }
        // packed key = dot*256 + c, c = sub*32 + rofs (uniform; bit 2 = hq slot)
        const int cbse = sub * 32;
        if (hasdiag) {
            #pragma unroll
            for (int r = 0; r < 16; ++r) {
                const int rofs = (r & 3) + 8 * (r >> 2);
                const int c = cbse + rofs;
                const int lrf = c + hq;
                int k0 = a0[r] * 256 + c; if (lrf == ilocb)       k0 = (int)0x80000000;
                int k1 = a1[r] * 256 + c; if (lrf == ilocb + 32)  k1 = (int)0x80000000;
                int k2 = a2[r] * 256 + c; if (lrf == ilocb + 64)  k2 = (int)0x80000000;
                int k3 = a3[r] * 256 + c; if (lrf == ilocb + 96)  k3 = (int)0x80000000;
                bd0 = imax(bd0, k0); bd1 = imax(bd1, k1);
                bd2 = imax(bd2, k2); bd3 = imax(bd3, k3);
            }
        } else {
            #pragma unroll
            for (int r = 0; r < 16; r += 2) {
                const int cA = cbse + ((r & 3) + 8 * (r >> 2));
                const int cB = cbse + (((r + 1) & 3) + 8 * ((r + 1) >> 2));
                bd0 = imax(imax(a0[r] * 256 + cA, a0[r + 1] * 256 + cB), bd0);
                bd1 = imax(imax(a1[r] * 256 + cA, a1[r + 1] * 256 + cB), bd1);
                bd2 = imax(imax(a2[r] * 256 + cA, a2[r + 1] * 256 + cB), bd2);
                bd3 = imax(imax(a3[r] * 256 + cA, a3[r + 1] * 256 + cB), bd3);
            }
        }
    }

    // restore hq bit, merge the two k-halves, plain-store per-slice winners
    ull* prow = part + (size_t)sb * NB;
    int bd[4] = {bd0 | hq, bd1 | hq, bd2 | hq, bd3 | hq};
    #pragma unroll
    for (int g = 0; g < 4; ++g) {
        int b = bd[g];
        const int o = __shfl_xor(b, 32);
        b = imax(b, o);
        if (lane < 32) {
            const unsigned uk = (unsigned)b ^ 0x80000000u;
            const unsigned j = (unsigned)(sbase + (b & 255));
            prow[colbase + g * 32 + col] = ((ull)uk << 32) | j;
        }
    }
}

// ---------------- Phase C: merge slices + exact fp32 distances ----------------
// grid NB/16 = 512 blocks; 4 waves/block; each wave handles 4 rows.
__global__ __launch_bounds__(256) void koleo_dist(const float* __restrict__ s,
                                                  const float* __restrict__ norms,
                                                  const ull* __restrict__ part,
                                                  float* __restrict__ partial) {
    __shared__ float wsums[4];
    const int w = threadIdx.x >> 6, lane = threadIdx.x & 63;
    float acc = 0.f;
    #pragma unroll
    for (int t = 0; t < 4; ++t) {
        const int i = blockIdx.x * 16 + w * 4 + t;
        // merge the 32 per-slice winners for row i (u64 butterfly max)
        ull k = part[(size_t)(lane & 31) * NB + i];
        #pragma unroll
        for (int m = 1; m < 32; m <<= 1) {
            const ull o = __shfl_xor(k, m);
            if (o > k) k = o;
        }
        const int j = (int)(k & 0xFFFFFFFFull);
        const float sci = 1.0f / (norms[i] + EPSF);
        const float scj = 1.0f / (norms[j] + EPSF);
        const float4 vi = *(const float4*)(s + i * ND + lane * 4);
        const float4 vj = *(const float4*)(s + j * ND + lane * 4);
        const float dx = vi.x * sci - vj.x * scj;
        const float dy = vi.y * sci - vj.y * scj;
        const float dz = vi.z * sci - vj.z * scj;
        const float dw = vi.w * sci - vj.w * scj;
        float d2 = dx * dx + dy * dy + dz * dz + dw * dw;
        #pragma unroll
        for (int mask = 32; mask; mask >>= 1) d2 += __shfl_xor(d2, mask);
        acc += -logf(sqrtf(d2) + EPSF + EPSF);
    }
    if (lane == 0) wsums[w] = acc;
    __syncthreads();
    if (threadIdx.x == 0) partial[blockIdx.x] = wsums[0] + wsums[1] + wsums[2] + wsums[3];
}

// ---------------- Phase D: final reduce (512 partials) ------------------------
__global__ __launch_bounds__(512) void koleo_final(const float* __restrict__ partial,
                                                   float* __restrict__ out) {
    __shared__ float w8[8];
    float v = partial[threadIdx.x];
    #pragma unroll
    for (int mask = 32; mask; mask >>= 1) v += __shfl_xor(v, mask);
    if ((threadIdx.x & 63) == 0) w8[threadIdx.x >> 6] = v;
    __syncthreads();
    if (threadIdx.x == 0) {
        float t = 0.f;
        #pragma unroll
        for (int k = 0; k < 8; ++k) t += w8[k];
        out[0] = t / (float)NB;
    }
}

extern "C" void kernel_launch(void* const* d_in, const int* in_sizes, int n_in,
                              void* d_out, int out_size, void* d_ws, size_t ws_size,
                              hipStream_t stream) {
    const float* s = (const float*)d_in[0];
    float* out = (float*)d_out;
    char* ws = (char*)d_ws;

    // ws layout
    char* qt = ws;                                                          // 2 MiB tiled i8
    float* norms = (float*)(ws + 2 * 1024 * 1024);                          // 32 KiB
    ull* part = (ull*)(ws + 2 * 1024 * 1024 + 32 * 1024);                   // 2 MiB (32 x 8192 u64)
    float* partial = (float*)(ws + 4 * 1024 * 1024 + 64 * 1024);            // 2 KiB

    koleo_normalize<<<NB / 4, 256, 0, stream>>>(s, (unsigned int*)qt, norms);
    koleo_argmax<<<dim3(NB / WCOLS, NSL), 64, 0, stream>>>((const i32x4*)qt, part);
    koleo_dist<<<NB / 16, 256, 0, stream>>>(s, norms, part, partial);
    koleo_final<<<1, 512, 0, stream>>>(partial, out);
}